// Round 3
// baseline (1070.979 us; speedup 1.0000x reference)
//
#include <hip/hip_runtime.h>

typedef _Float16 f16;
typedef __attribute__((ext_vector_type(4))) _Float16 f16x4;
typedef __attribute__((ext_vector_type(8))) _Float16 f16x8;
typedef __attribute__((ext_vector_type(4))) float f32x4;

#define NB 4
#define SS 2048
#define DM 768
#define NH 12
#define HDIM 64
#define MROWS 8192

// workspace layout (bytes)
#define XH_OFF   0ull
#define WT_OFF   12582912ull
#define QH_OFF   17301504ull
#define KH_OFF   29884416ull
#define VH_OFF   42467328ull
#define VT_OFF   55050240ull
#define AO_OFF   67633152ull

__device__ __forceinline__ void async_copy16(const void* g, void* l) {
  __builtin_amdgcn_global_load_lds((const __attribute__((address_space(1))) void*)g,
                                   (__attribute__((address_space(3))) void*)l, 16, 0, 0);
}

// ---------------- x -> fp16 ----------------
__global__ void k_cvt_x(const float* __restrict__ x, f16* __restrict__ xh, int n4) {
  int i = blockIdx.x * 256 + threadIdx.x;
  if (i >= n4) return;
  float4 v = ((const float4*)x)[i];
  f16x4 o;
  o.x = (f16)v.x; o.y = (f16)v.y; o.z = (f16)v.z; o.w = (f16)v.w;
  ((f16x4*)xh)[i] = o;
}

// ---------------- weights -> fp16, transposed to [N][K] ----------------
__global__ void k_wt(const float* __restrict__ Wq, const float* __restrict__ Wk,
                     const float* __restrict__ Wv, const float* __restrict__ Wo,
                     f16* __restrict__ wt) {
  __shared__ float t[32][33];
  const int w = blockIdx.z;
  const float* W = (w == 0) ? Wq : (w == 1) ? Wk : (w == 2) ? Wv : Wo;
  const int bx = blockIdx.x * 32, by = blockIdx.y * 32;
  const int tx = threadIdx.x, ty = threadIdx.y;
  t[ty][tx] = W[(size_t)(by + ty) * DM + bx + tx];
  __syncthreads();
  wt[(size_t)w * DM * DM + (size_t)(bx + ty) * DM + by + tx] = (f16)t[tx][ty];
}

// ---------------- 128x128 MFMA GEMM, 2-phase double-buffered ----------------
template<int MODE>
__global__ __launch_bounds__(256) void k_gemm(const f16* __restrict__ A,
                                              const f16* __restrict__ Wt,
                                              float* __restrict__ outF,
                                              f16* __restrict__ Qh,
                                              f16* __restrict__ Kh,
                                              f16* __restrict__ Vh) {
  __shared__ f16 Al[2][128 * 32];
  __shared__ f16 Bl[2][128 * 32];
  const int tid = threadIdx.x, lane = tid & 63, wid = tid >> 6;
  const int mt = blockIdx.x;
  int w, ntile;
  if (MODE == 0) { w = blockIdx.y / 6; ntile = blockIdx.y % 6; }
  else           { w = 3;              ntile = blockIdx.y; }
  const f16* Wb = Wt + (size_t)w * DM * DM;

  f32x4 acc[4][4] = {};
  const int wr = (wid >> 1) * 64, wc = (wid & 1) * 64;

  const int r0 = tid >> 2, c8 = (tid & 3) * 8;
  const f16* As0 = A  + (size_t)(mt * 128 + r0) * DM + c8;
  const f16* As1 = A  + (size_t)(mt * 128 + r0 + 64) * DM + c8;
  const f16* Bs0 = Wb + (size_t)(ntile * 128 + r0) * DM + c8;
  const f16* Bs1 = Wb + (size_t)(ntile * 128 + r0 + 64) * DM + c8;

  auto stage = [&](int bi, int k0) {
    async_copy16(As0 + k0, &Al[bi][wid * 512]);
    async_copy16(As1 + k0, &Al[bi][2048 + wid * 512]);
    async_copy16(Bs0 + k0, &Bl[bi][wid * 512]);
    async_copy16(Bs1 + k0, &Bl[bi][2048 + wid * 512]);
  };

  stage(0, 0);
  for (int k0 = 0, it = 0; k0 < DM; k0 += 32, ++it) {
    const int cur = it & 1;
    asm volatile("s_waitcnt vmcnt(0)" ::: "memory");
    __syncthreads();
    if (k0 + 32 < DM) stage(cur ^ 1, k0 + 32);
    f16x8 af[4], bfr[4];
#pragma unroll
    for (int r = 0; r < 4; ++r)
      af[r] = *(const f16x8*)&Al[cur][(wr + r * 16 + (lane & 15)) * 32 + (lane >> 4) * 8];
#pragma unroll
    for (int c = 0; c < 4; ++c)
      bfr[c] = *(const f16x8*)&Bl[cur][(wc + c * 16 + (lane & 15)) * 32 + (lane >> 4) * 8];
    __builtin_amdgcn_s_setprio(1);
#pragma unroll
    for (int r = 0; r < 4; ++r)
#pragma unroll
      for (int c = 0; c < 4; ++c)
        acc[r][c] = __builtin_amdgcn_mfma_f32_16x16x32_f16(af[r], bfr[c], acc[r][c], 0, 0, 0);
    __builtin_amdgcn_s_setprio(0);
  }

#pragma unroll
  for (int r = 0; r < 4; ++r)
#pragma unroll
    for (int c = 0; c < 4; ++c)
#pragma unroll
      for (int i = 0; i < 4; ++i) {
        const int gm = mt * 128 + wr + r * 16 + (lane >> 4) * 4 + i;
        const int gn = ntile * 128 + wc + c * 16 + (lane & 15);
        const float v = acc[r][c][i];
        if (MODE == 1) {
          outF[(size_t)gm * DM + gn] = v;
        } else {
          const int b = gm >> 11, s = gm & 2047;
          const int h = gn >> 6, d = gn & 63;
          const size_t idx = ((size_t)(b * NH + h) * SS + s) * HDIM + d;
          if (w == 0)      Qh[idx] = (f16)(v * 0.125f);
          else if (w == 1) Kh[idx] = (f16)v;
          else             Vh[idx] = (f16)v;
        }
      }
}

// ---------------- V [B,H,S,D] -> V^T [B,H,D,S] ----------------
__global__ void k_vt(const f16* __restrict__ Vh, f16* __restrict__ Vt) {
  const int lane = threadIdx.x & 63, wid = threadIdx.x >> 6;
  const int s = blockIdx.x * 64 + lane;
  const int bh = blockIdx.y;
#pragma unroll
  for (int p = 0; p < 2; ++p) {
    const int d0 = wid * 16 + p * 8;
    f16x8 v = *(const f16x8*)&Vh[((size_t)bh * SS + s) * HDIM + d0];
#pragma unroll
    for (int q = 0; q < 8; ++q)
      Vt[((size_t)bh * HDIM + d0 + q) * SS + s] = v[q];
  }
}

// ---------------- fused attention (swapped QK^T, per-lane softmax) ----------------
// grid (16, 48), 256 thr = 4 waves. Wave owns 32 q-rows (2 rt-tiles of 16, q = lane&15).
// sacc layout after mfma(K,Q): col(lane&15)=q, row=(lane>>4)*4+i = kv  -> logits f32x4 stores.
// PV as mfma(V^T, P): o col = q = lane&15 -> m/l/scal are per-lane scalars.
__global__ __launch_bounds__(256) void k_attn(const f16* __restrict__ Qh,
                                              const f16* __restrict__ Kh,
                                              const f16* __restrict__ Vt,
                                              const float* __restrict__ qm,
                                              float* __restrict__ logits,
                                              f16* __restrict__ AO) {
  __shared__ f16 Kl[2][64 * 64];
  __shared__ f16 Vl[2][64 * 64];
  __shared__ f16 Pl[4][16 * 76];   // stride 76 f16: conflict-light, 8B aligned
  const int tid = threadIdx.x, lane = tid & 63, wid = tid >> 6;
  const int qt = blockIdx.x, bh = blockIdx.y;
  const int b = bh / NH, h = bh - b * NH;
  const int q0 = qt * 128 + wid * 32;

  f16x8 qf[2][2];
#pragma unroll
  for (int rt = 0; rt < 2; ++rt)
#pragma unroll
    for (int ks = 0; ks < 2; ++ks)
      qf[rt][ks] = *(const f16x8*)&Qh[((size_t)bh * SS + q0 + rt * 16 + (lane & 15)) * HDIM +
                                      ks * 32 + (lane >> 4) * 8];

  float qmq[2];
#pragma unroll
  for (int rt = 0; rt < 2; ++rt)
    qmq[rt] = qm[b * SS + q0 + rt * 16 + (lane & 15)];

  float mrun[2] = {-3.0e38f, -3.0e38f}, lrun[2] = {0.f, 0.f};
  f32x4 o[2][4] = {};

  float* const logbase = logits + (size_t)bh * SS * SS;
  const char* const Kbase = (const char*)Kh + (size_t)bh * SS * HDIM * 2;
  const char* const Vbase = (const char*)Vt + (size_t)bh * HDIM * SS * 2;
  const int r0s = tid >> 3;
  const int wb0 = (tid & 7) * 16;

  auto STAGE = [&](int bi, int c) {
#pragma unroll
    for (int j = 0; j < 2; ++j) {
      const int r = r0s + j * 32;
      const int swb = wb0 ^ ((r & 7) << 4);   // pre-swizzle SOURCE, LDS linear (G21)
      async_copy16(Kbase + (size_t)(c * 64 + r) * 128 + swb,
                   (char*)&Kl[bi][0] + wid * 1024 + j * 4096);
      async_copy16(Vbase + (size_t)r * 4096 + c * 128 + swb,
                   (char*)&Vl[bi][0] + wid * 1024 + j * 4096);
    }
  };

  STAGE(0, 0);
  for (int c = 0; c < 32; ++c) {
    const int cur = c & 1;
    asm volatile("s_waitcnt vmcnt(0)" ::: "memory");
    __syncthreads();
    if (c + 1 < 32) STAGE(cur ^ 1, c + 1);

    f16x8 kf[4][2], vf[4][2];
#pragma unroll
    for (int t = 0; t < 4; ++t)
#pragma unroll
      for (int ks = 0; ks < 2; ++ks) {
        const int row = t * 16 + (lane & 15);
        const int byt = row * 128 + ((ks * 64 + (lane >> 4) * 16) ^ ((row & 7) << 4));
        kf[t][ks] = *(const f16x8*)((const char*)&Kl[cur][0] + byt);
        vf[t][ks] = *(const f16x8*)((const char*)&Vl[cur][0] + byt);
      }

    float4 qmk4[4];
#pragma unroll
    for (int ct = 0; ct < 4; ++ct)
      qmk4[ct] = *(const float4*)&qm[b * SS + c * 64 + ct * 16 + (lane >> 4) * 4];

    f32x4 sacc[2][4];
    __builtin_amdgcn_s_setprio(1);
#pragma unroll
    for (int rt = 0; rt < 2; ++rt)
#pragma unroll
      for (int ct = 0; ct < 4; ++ct) {
        f32x4 z = {};
        z = __builtin_amdgcn_mfma_f32_16x16x32_f16(kf[ct][0], qf[rt][0], z, 0, 0, 0);
        sacc[rt][ct] = __builtin_amdgcn_mfma_f32_16x16x32_f16(kf[ct][1], qf[rt][1], z, 0, 0, 0);
      }
    __builtin_amdgcn_s_setprio(0);

    // raw logits: lane's 4 acc elems are 4 consecutive kv columns -> one f32x4 nt-store
#pragma unroll
    for (int rt = 0; rt < 2; ++rt)
#pragma unroll
      for (int ct = 0; ct < 4; ++ct) {
        const int gq = q0 + rt * 16 + (lane & 15);
        const int gk = c * 64 + ct * 16 + (lane >> 4) * 4;
        __builtin_nontemporal_store(sacc[rt][ct], (f32x4*)(logbase + (size_t)gq * SS + gk));
      }

#pragma unroll
    for (int rt = 0; rt < 2; ++rt) {
      float p[4][4];
      float pm = -3.0e38f;
#pragma unroll
      for (int ct = 0; ct < 4; ++ct)
#pragma unroll
        for (int i = 0; i < 4; ++i) {
          p[ct][i] = sacc[rt][ct][i] + (qmq[rt] * ((const float*)&qmk4[ct])[i] - 1.f) * 100000.f;
          pm = fmaxf(pm, p[ct][i]);
        }
      pm = fmaxf(pm, __shfl_xor(pm, 16));
      pm = fmaxf(pm, __shfl_xor(pm, 32));
      const float mnew = fmaxf(mrun[rt], pm);
      const float scal = __expf(mrun[rt] - mnew);
      mrun[rt] = mnew;
      float rs = 0.f;
#pragma unroll
      for (int ct = 0; ct < 4; ++ct)
#pragma unroll
        for (int i = 0; i < 4; ++i) {
          p[ct][i] = __expf(p[ct][i] - mnew);
          rs += p[ct][i];
        }
      rs += __shfl_xor(rs, 16);
      rs += __shfl_xor(rs, 32);
      lrun[rt] = lrun[rt] * scal + rs;
#pragma unroll
      for (int dt = 0; dt < 4; ++dt)
#pragma unroll
        for (int i = 0; i < 4; ++i) o[rt][dt][i] *= scal;

      // P -> per-wave LDS as packed b64 writes, read back as B-fragments
      f16* pw = Pl[wid];
#pragma unroll
      for (int ct = 0; ct < 4; ++ct) {
        f16x4 pk;
#pragma unroll
        for (int i = 0; i < 4; ++i) pk[i] = (f16)p[ct][i];
        *(f16x4*)&pw[(lane & 15) * 76 + ct * 16 + (lane >> 4) * 4] = pk;
      }
      asm volatile("s_waitcnt lgkmcnt(0)" ::: "memory");
      const f16x8 pf0 = *(const f16x8*)&pw[(lane & 15) * 76 + (lane >> 4) * 8];
      const f16x8 pf1 = *(const f16x8*)&pw[(lane & 15) * 76 + 32 + (lane >> 4) * 8];
      __builtin_amdgcn_s_setprio(1);
#pragma unroll
      for (int dt = 0; dt < 4; ++dt) {
        o[rt][dt] = __builtin_amdgcn_mfma_f32_16x16x32_f16(vf[dt][0], pf0, o[rt][dt], 0, 0, 0);
        o[rt][dt] = __builtin_amdgcn_mfma_f32_16x16x32_f16(vf[dt][1], pf1, o[rt][dt], 0, 0, 0);
      }
      __builtin_amdgcn_s_setprio(0);
    }
  }

#pragma unroll
  for (int rt = 0; rt < 2; ++rt) {
    const float inv = 1.0f / lrun[rt];
    const int gq = q0 + rt * 16 + (lane & 15);
#pragma unroll
    for (int dt = 0; dt < 4; ++dt) {
      f16x4 ov;
#pragma unroll
      for (int i = 0; i < 4; ++i) ov[i] = (f16)(o[rt][dt][i] * inv);
      *(f16x4*)&AO[((size_t)b * SS + gq) * DM + h * HDIM + dt * 16 + (lane >> 4) * 4] = ov;
    }
  }
}

extern "C" void kernel_launch(void* const* d_in, const int* in_sizes, int n_in,
                              void* d_out, int out_size, void* d_ws, size_t ws_size,
                              hipStream_t stream) {
  const float* x  = (const float*)d_in[0];
  const float* qm = (const float*)d_in[1];
  float* out    = (float*)d_out;
  float* logits = out + 6291456;

  char* ws = (char*)d_ws;
  f16* xh = (f16*)(ws + XH_OFF);
  f16* wt = (f16*)(ws + WT_OFF);
  f16* qh = (f16*)(ws + QH_OFF);
  f16* kh = (f16*)(ws + KH_OFF);
  f16* vh = (f16*)(ws + VH_OFF);
  f16* vt = (f16*)(ws + VT_OFF);
  f16* ao = (f16*)(ws + AO_OFF);

  const int n4 = MROWS * DM / 4;
  k_cvt_x<<<(n4 + 255) / 256, 256, 0, stream>>>(x, xh, n4);
  k_wt<<<dim3(24, 24, 4), dim3(32, 32), 0, stream>>>((const float*)d_in[2], (const float*)d_in[3],
                                                     (const float*)d_in[4], (const float*)d_in[5], wt);
  k_gemm<0><<<dim3(64, 18), 256, 0, stream>>>(xh, wt, nullptr, qh, kh, vh);
  k_vt<<<dim3(32, 48), 256, 0, stream>>>(vh, vt);
  k_attn<<<dim3(16, 48), 256, 0, stream>>>(qh, kh, vt, qm, logits, ao);
  k_gemm<1><<<dim3(64, 6), 256, 0, stream>>>(ao, wt, out, nullptr, nullptr, nullptr);
}